// Round 7
// baseline (6147.305 us; speedup 1.0000x reference)
//
#include <hip/hip_runtime.h>
#include <stdint.h>

typedef __attribute__((ext_vector_type(4))) float f32x4;
typedef __attribute__((ext_vector_type(8))) short s16x8;
typedef __attribute__((ext_vector_type(4))) unsigned short u16x4;
typedef __attribute__((ext_vector_type(4))) unsigned int u32x4;

#define T_SEQ 1024
#define HID 512

__device__ __forceinline__ unsigned short f2bf(float f) {
  uint32_t u = __float_as_uint(f);
  u += 0x7fffu + ((u >> 16) & 1u);  // round-to-nearest-even
  return (unsigned short)(u >> 16);
}
__device__ __forceinline__ float sigf(float x) { return 1.f / (1.f + __expf(-x)); }
__device__ __forceinline__ float tanhfast(float x) {
  float e = __expf(2.f * x);
  return (e - 1.f) / (e + 1.f);
}

#define ASTORE(p, v) __hip_atomic_store((p), (v), __ATOMIC_RELAXED, __HIP_MEMORY_SCOPE_AGENT)
#define MFMA(a, b, c) __builtin_amdgcn_mfma_f32_16x16x32_bf16((a), (b), (c), 0, 0, 0)

// System-scope 16B load (sc0 sc1): bypasses L1 AND the non-coherent per-XCD L2 -> always
// re-fetches from the coherence point. PROVEN (round 4). sc0-alone is L1-hittable (round-6 bug).
__device__ __forceinline__ u32x4 load_coh16(const unsigned int* p) {
  u32x4 r;
  asm volatile("global_load_dwordx4 %0, %1, off sc0 sc1" : "=v"(r) : "v"(p) : "memory");
  return r;
}
#define VM_WAIT0 do { asm volatile("s_waitcnt vmcnt(0)" ::: "memory"); \
                      __builtin_amdgcn_sched_barrier(0); } while (0)

#define GLL(gp, lp)                                                      \
  __builtin_amdgcn_global_load_lds(                                     \
      (const __attribute__((address_space(1))) void*)(gp),              \
      (__attribute__((address_space(3))) void*)(lp), 16, 0, 0)

// ---------------- small prep kernels ----------------
__global__ __launch_bounds__(256) void embed_kernel(const int* __restrict__ inp,
                                                    const float* __restrict__ wte,
                                                    unsigned short* __restrict__ xbf) {
  const int m = blockIdx.x;  // m = b*1024 + t
  const int idx = inp[m];
  const float* src = wte + (size_t)idx * HID;
  unsigned short* dst = xbf + (size_t)m * HID;
  const int e = threadIdx.x;
  dst[e] = f2bf(src[e]);
  dst[e + 256] = f2bf(src[e + 256]);
}

__global__ __launch_bounds__(256) void cvt_bf16_kernel(const float* __restrict__ src,
                                                       unsigned short* __restrict__ dst,
                                                       int n4) {
  const int i = blockIdx.x * 256 + threadIdx.x;
  if (i >= n4) return;
  f32x4 v = ((const f32x4*)src)[i];
  u16x4 o;
  o.x = f2bf(v.x); o.y = f2bf(v.y); o.z = f2bf(v.z); o.w = f2bf(v.w);
  ((u16x4*)dst)[i] = o;
}

__global__ __launch_bounds__(256) void bias_sum_kernel(const float* __restrict__ a,
                                                       const float* __restrict__ b,
                                                       float* __restrict__ o, int n) {
  const int i = blockIdx.x * 256 + threadIdx.x;
  if (i < n) o[i] = a[i] + b[i];
}

// ---------------- bf16 MFMA GEMM:  C[m][n] = sum_k A[m][k]*B[n][k] + bias[n] ----------------
// MODE 0: C row = m. MODE 1: m = t*8+b -> C row = b*1024+t.
template <int MODE>
__global__ __launch_bounds__(256) void gemm_bt(const unsigned short* __restrict__ A,
                                               const unsigned short* __restrict__ B,
                                               float* __restrict__ C,
                                               const float* __restrict__ bias,
                                               int M, int N, int K) {
  __shared__ unsigned short As[128 * 32];
  __shared__ unsigned short Bs[128 * 32];
  const int nTiles = N >> 7;
  const int mt = blockIdx.x / nTiles;
  const int nt = blockIdx.x - mt * nTiles;
  const int m0 = mt << 7, n0 = nt << 7;
  const int tid = threadIdx.x;
  const int wave = tid >> 6, lane = tid & 63;
  const int wm = wave >> 1, wn = wave & 1;

  const int c1 = wave * 64 + lane;
  const int c2 = 256 + c1;
  const unsigned short* gA1 = A + (size_t)(m0 + (c1 >> 2)) * K + (c1 & 3) * 8;
  const unsigned short* gA2 = A + (size_t)(m0 + (c2 >> 2)) * K + (c2 & 3) * 8;
  const unsigned short* gB1 = B + (size_t)(n0 + (c1 >> 2)) * K + (c1 & 3) * 8;
  const unsigned short* gB2 = B + (size_t)(n0 + (c2 >> 2)) * K + (c2 & 3) * 8;
  unsigned short* lA1 = As + wave * 512;
  unsigned short* lA2 = As + 2048 + wave * 512;
  unsigned short* lB1 = Bs + wave * 512;
  unsigned short* lB2 = Bs + 2048 + wave * 512;

  f32x4 acc[4][4] = {};
  const int row_lo = lane & 15;
  const int kq = (lane >> 4) * 8;

  for (int k0 = 0; k0 < K; k0 += 32) {
    GLL(gA1 + k0, lA1);
    GLL(gA2 + k0, lA2);
    GLL(gB1 + k0, lB1);
    GLL(gB2 + k0, lB2);
    __syncthreads();
    s16x8 af[4], bfr[4];
#pragma unroll
    for (int f = 0; f < 4; ++f) {
      af[f] = *(const s16x8*)(As + (wm * 64 + f * 16 + row_lo) * 32 + kq);
      bfr[f] = *(const s16x8*)(Bs + (wn * 64 + f * 16 + row_lo) * 32 + kq);
    }
#pragma unroll
    for (int i = 0; i < 4; ++i)
#pragma unroll
      for (int j = 0; j < 4; ++j)
        acc[i][j] = MFMA(af[i], bfr[j], acc[i][j]);
    __syncthreads();
  }

  float bv[4];
#pragma unroll
  for (int j = 0; j < 4; ++j) bv[j] = bias[n0 + wn * 64 + j * 16 + row_lo];
  const int rbase = (lane >> 4) * 4;
#pragma unroll
  for (int i = 0; i < 4; ++i) {
#pragma unroll
    for (int r = 0; r < 4; ++r) {
      const int m = m0 + wm * 64 + i * 16 + rbase + r;
      const size_t row = MODE == 1 ? ((size_t)(m & 7) * T_SEQ + (m >> 3)) : (size_t)m;
      float* cp = C + row * (size_t)N;
#pragma unroll
      for (int j = 0; j < 4; ++j) cp[n0 + wn * 64 + j * 16 + row_lo] = acc[i][j][r] + bv[j];
    }
  }
}

// ---------------- persistent fused 2-layer LSTM ----------------
// 32 WGs x 256 thr (16 hidden units each, BOTH layers). Round-4-proven sync: tagged u32
// (bf16 | (step+1)<<16) stored relaxed-agent, polled with sc0+sc1 loads (coherence point).
// Pipeline: iteration t = { poll h1(t-1), h2(t-3) } -> L1 step t -> store h1(t)
//           -> L2 step t-2 (h1(t-2) from ping-pong LDS buffer) -> store h2(t-2).
// One exposed MALL round trip per step (h1); h2 has a full iteration of slack.
__global__ __launch_bounds__(256, 1) void lstm_fused(
    const float* __restrict__ xg1,             // [b*1024+t][2048]
    const unsigned short* __restrict__ whh1,
    const unsigned short* __restrict__ wih2,
    const unsigned short* __restrict__ whh2,
    const float* __restrict__ bias2,           // b_ih+b_hh layer 2
    unsigned int* __restrict__ h1T,            // [t][8][512] tagged u32
    unsigned int* __restrict__ h2T,            // [t][8][512] tagged u32
    unsigned short* __restrict__ h2out) {      // [t*8+b][512] bf16 (FC input)
  __shared__ __align__(16) char lds1[2][8192];  // h1 ping-pong: [8 batch][512] bf16, swizzled
  __shared__ __align__(16) char lds2[8192];     // h2
  __shared__ float GT1[512];                    // [gate][unit16][batch8]
  __shared__ float GT2[512];

  const int tid = threadIdx.x;
  const int wg = blockIdx.x;
  const int g = tid >> 6, l = tid & 63;   // wave = gate (i,f,g,o)
  const int unit = l & 15, grp = l >> 4;  // B col = unit; k-quarter = grp
  const int u0 = wg * 16;
  const int row = l & 7;                  // A row (batch); lanes 8-15 duplicate rows

  // ---- resident weight B-fragments (48 x 4 VGPR) ----
  s16x8 b1[16], b2i[16], b2h[16];
  {
    const size_t grow = (size_t)(g * 512 + u0 + unit) * 512;
#pragma unroll
    for (int kt = 0; kt < 16; ++kt) {
      b1[kt] = *(const s16x8*)(whh1 + grow + kt * 32 + grp * 8);
      b2i[kt] = *(const s16x8*)(wih2 + grow + kt * 32 + grp * 8);
      b2h[kt] = *(const s16x8*)(whh2 + grow + kt * 32 + grp * 8);
    }
  }

  // ---- pointwise constants (wave 0): lane -> (batch pb, unit-half pu), units u = r*8+pu ----
  const int pb = l & 7, pu = l >> 3;
  float bias_g[2][4];
  if (g == 0) {
#pragma unroll
    for (int r = 0; r < 2; ++r)
#pragma unroll
      for (int gg = 0; gg < 4; ++gg)
        bias_g[r][gg] = bias2[gg * 512 + u0 + r * 8 + pu];
  }
  float c1a = 0.f, c1b = 0.f, c2a = 0.f, c2b = 0.f;

  // ---- staging ids: thread -> (row sr, 16-u32 chunk sc); XOR-swizzled LDS ----
  const int sr = tid & 7, sc = tid >> 3;
  const int so0 = (sr * 1024 + sc * 32) ^ (sr << 4);
  const int so1 = (sr * 1024 + sc * 32 + 16) ^ (sr << 4);
  const int srcoff = sr * 512 + sc * 16;

  for (int t = 0; t <= T_SEQ + 1; ++t) {
    const int cur = t & 1;

    // ---- xg prefetch for L1 step t (issued before the poll) ----
    float xv[2][4];
    if (g == 0 && t < T_SEQ) {
#pragma unroll
      for (int r = 0; r < 2; ++r)
#pragma unroll
        for (int gg = 0; gg < 4; ++gg)
          xv[r][gg] = xg1[((size_t)pb * T_SEQ + t) * 2048 + gg * 512 + u0 + r * 8 + pu];
    }

    // ---- poll + stage: h1(t-1) [tag t] and h2(t-3) [tag t-2] ----
    const bool need1 = (t >= 1) && (t <= T_SEQ);
    const bool need2 = (t >= 3);
    if (need1 || need2) {
      const unsigned int* s1 = h1T + (size_t)(t - 1) * 4096 + srcoff;
      const unsigned int* s2 = h2T + (size_t)(t - 3) * 4096 + srcoff;
      const unsigned int tg1 = (unsigned int)t, tg2 = (unsigned int)(t - 2);
      u32x4 d0 = {}, d1 = {}, d2 = {}, d3 = {}, e0 = {}, e1 = {}, e2 = {}, e3 = {};
      int spin = 0;
      for (;;) {
        if (need1) {
          d0 = load_coh16(s1); d1 = load_coh16(s1 + 4);
          d2 = load_coh16(s1 + 8); d3 = load_coh16(s1 + 12);
        }
        if (need2) {
          e0 = load_coh16(s2); e1 = load_coh16(s2 + 4);
          e2 = load_coh16(s2 + 8); e3 = load_coh16(s2 + 12);
        }
        VM_WAIT0;
        bool ok = true;
        if (need1) {
#pragma unroll
          for (int j = 0; j < 4; ++j) {
            ok &= (d0[j] >> 16) == tg1; ok &= (d1[j] >> 16) == tg1;
            ok &= (d2[j] >> 16) == tg1; ok &= (d3[j] >> 16) == tg1;
          }
        }
        if (need2) {
#pragma unroll
          for (int j = 0; j < 4; ++j) {
            ok &= (e0[j] >> 16) == tg2; ok &= (e1[j] >> 16) == tg2;
            ok &= (e2[j] >> 16) == tg2; ok &= (e3[j] >> 16) == tg2;
          }
        }
        if (__ballot(ok) == ~0ULL) break;
        if (++spin > (1 << 14)) break;  // insurance: fail fast, never hang
        __builtin_amdgcn_s_sleep(1);
      }
      if (need1) {
        *(u32x4*)(lds1[cur] + so0) =
            u32x4{(d0[0] & 0xffffu) | (d0[1] << 16), (d0[2] & 0xffffu) | (d0[3] << 16),
                  (d1[0] & 0xffffu) | (d1[1] << 16), (d1[2] & 0xffffu) | (d1[3] << 16)};
        *(u32x4*)(lds1[cur] + so1) =
            u32x4{(d2[0] & 0xffffu) | (d2[1] << 16), (d2[2] & 0xffffu) | (d2[3] << 16),
                  (d3[0] & 0xffffu) | (d3[1] << 16), (d3[2] & 0xffffu) | (d3[3] << 16)};
      }
      if (need2) {
        *(u32x4*)(lds2 + so0) =
            u32x4{(e0[0] & 0xffffu) | (e0[1] << 16), (e0[2] & 0xffffu) | (e0[3] << 16),
                  (e1[0] & 0xffffu) | (e1[1] << 16), (e1[2] & 0xffffu) | (e1[3] << 16)};
        *(u32x4*)(lds2 + so1) =
            u32x4{(e2[0] & 0xffffu) | (e2[1] << 16), (e2[2] & 0xffffu) | (e2[3] << 16),
                  (e3[0] & 0xffffu) | (e3[1] << 16), (e3[2] & 0xffffu) | (e3[3] << 16)};
      }
    }
    if (t == 0) {  // h1(-1) = 0
      *(u32x4*)(lds1[0] + so0) = u32x4{0, 0, 0, 0};
      *(u32x4*)(lds1[0] + so1) = u32x4{0, 0, 0, 0};
    }
    if (t == 2) {  // h2(-1) = 0
      *(u32x4*)(lds2 + so0) = u32x4{0, 0, 0, 0};
      *(u32x4*)(lds2 + so1) = u32x4{0, 0, 0, 0};
    }
    __syncthreads();  // staging complete

    // ---- L1 MFMA step t: gates = h1(t-1) @ Whh1^T ----
    if (t < T_SEQ) {
      const char* hb = lds1[cur];
      f32x4 q0 = {}, q1 = {}, q2 = {}, q3 = {};
#pragma unroll
      for (int kt = 0; kt < 16; kt += 4) {
        s16x8 x0 = *(const s16x8*)(hb + ((row * 1024 + (kt + 0) * 64 + grp * 16) ^ (row << 4)));
        s16x8 x1 = *(const s16x8*)(hb + ((row * 1024 + (kt + 1) * 64 + grp * 16) ^ (row << 4)));
        s16x8 x2 = *(const s16x8*)(hb + ((row * 1024 + (kt + 2) * 64 + grp * 16) ^ (row << 4)));
        s16x8 x3 = *(const s16x8*)(hb + ((row * 1024 + (kt + 3) * 64 + grp * 16) ^ (row << 4)));
        q0 = MFMA(x0, b1[kt + 0], q0);
        q1 = MFMA(x1, b1[kt + 1], q1);
        q2 = MFMA(x2, b1[kt + 2], q2);
        q3 = MFMA(x3, b1[kt + 3], q3);
      }
      f32x4 acc = (q0 + q1) + (q2 + q3);
      if (grp < 2) *(f32x4*)(GT1 + g * 128 + unit * 8 + grp * 4) = acc;
    }
    __syncthreads();  // GT1 ready

    // ---- pointwise L1 (wave 0) + tagged h1 store: propagates during the L2 section ----
    if (g == 0 && t < T_SEQ) {
#pragma unroll
      for (int r = 0; r < 2; ++r) {
        const int u = r * 8 + pu;
        float gi = GT1[0 + u * 8 + pb] + xv[r][0];
        float gf = GT1[128 + u * 8 + pb] + xv[r][1];
        float gv = GT1[256 + u * 8 + pb] + xv[r][2];
        float go = GT1[384 + u * 8 + pb] + xv[r][3];
        float& cc = r ? c1b : c1a;
        cc = sigf(gf) * cc + sigf(gi) * tanhfast(gv);
        const float hv = sigf(go) * tanhfast(cc);
        ASTORE(h1T + (size_t)t * 4096 + pb * 512 + u0 + u,
               (unsigned int)f2bf(hv) | ((unsigned int)(t + 1) << 16));
      }
    }

    // ---- L2 MFMA step s = t-2: gates = h1(s) @ Wih2^T + h2(s-1) @ Whh2^T ----
    if (t >= 2) {
      const char* ha = lds1[cur ^ 1];  // h1(t-2), staged last iteration
      f32x4 q0 = {}, q1 = {}, q2 = {}, q3 = {};
#pragma unroll
      for (int kt = 0; kt < 16; kt += 4) {
        s16x8 x0 = *(const s16x8*)(ha + ((row * 1024 + (kt + 0) * 64 + grp * 16) ^ (row << 4)));
        s16x8 x1 = *(const s16x8*)(ha + ((row * 1024 + (kt + 1) * 64 + grp * 16) ^ (row << 4)));
        s16x8 x2 = *(const s16x8*)(ha + ((row * 1024 + (kt + 2) * 64 + grp * 16) ^ (row << 4)));
        s16x8 x3 = *(const s16x8*)(ha + ((row * 1024 + (kt + 3) * 64 + grp * 16) ^ (row << 4)));
        q0 = MFMA(x0, b2i[kt + 0], q0);
        q1 = MFMA(x1, b2i[kt + 1], q1);
        q2 = MFMA(x2, b2i[kt + 2], q2);
        q3 = MFMA(x3, b2i[kt + 3], q3);
      }
#pragma unroll
      for (int kt = 0; kt < 16; kt += 4) {
        s16x8 x0 = *(const s16x8*)(lds2 + ((row * 1024 + (kt + 0) * 64 + grp * 16) ^ (row << 4)));
        s16x8 x1 = *(const s16x8*)(lds2 + ((row * 1024 + (kt + 1) * 64 + grp * 16) ^ (row << 4)));
        s16x8 x2 = *(const s16x8*)(lds2 + ((row * 1024 + (kt + 2) * 64 + grp * 16) ^ (row << 4)));
        s16x8 x3 = *(const s16x8*)(lds2 + ((row * 1024 + (kt + 3) * 64 + grp * 16) ^ (row << 4)));
        q0 = MFMA(x0, b2h[kt + 0], q0);
        q1 = MFMA(x1, b2h[kt + 1], q1);
        q2 = MFMA(x2, b2h[kt + 2], q2);
        q3 = MFMA(x3, b2h[kt + 3], q3);
      }
      f32x4 acc = (q0 + q1) + (q2 + q3);
      if (grp < 2) *(f32x4*)(GT2 + g * 128 + unit * 8 + grp * 4) = acc;
    }
    __syncthreads();  // GT2 ready; also: all LDS-tile reads done before next staging overwrite

    // ---- pointwise L2 (wave 0), tagged h2 store + FC-input store ----
    if (g == 0 && t >= 2) {
      const int s = t - 2;
#pragma unroll
      for (int r = 0; r < 2; ++r) {
        const int u = r * 8 + pu;
        float gi = GT2[0 + u * 8 + pb] + bias_g[r][0];
        float gf = GT2[128 + u * 8 + pb] + bias_g[r][1];
        float gv = GT2[256 + u * 8 + pb] + bias_g[r][2];
        float go = GT2[384 + u * 8 + pb] + bias_g[r][3];
        float& cc = r ? c2b : c2a;
        cc = sigf(gf) * cc + sigf(gi) * tanhfast(gv);
        const float hv = sigf(go) * tanhfast(cc);
        const unsigned int hb16 = f2bf(hv);
        ASTORE(h2T + (size_t)s * 4096 + pb * 512 + u0 + u,
               hb16 | ((unsigned int)(s + 1) << 16));
        h2out[((size_t)s * 8 + pb) * 512 + u0 + u] = (unsigned short)hb16;
      }
    }
  }
}

// ---------------- host launch ----------------
extern "C" void kernel_launch(void* const* d_in, const int* in_sizes, int n_in,
                              void* d_out, int out_size, void* d_ws, size_t ws_size,
                              hipStream_t stream) {
  (void)in_sizes; (void)n_in; (void)out_size; (void)ws_size;
  const int* inp = (const int*)d_in[0];
  const float* wte = (const float*)d_in[1];
  const float* W_ih = (const float*)d_in[2];
  const float* W_hh = (const float*)d_in[3];
  const float* b_ih = (const float*)d_in[4];
  const float* b_hh = (const float*)d_in[5];
  const float* fc_w = (const float*)d_in[6];
  const float* fc_b = (const float*)d_in[7];
  float* out = (float*)d_out;

  // Large intermediates inside d_out (1 GB; fully overwritten by the final FC GEMM).
  char* ob = (char*)d_out;
  float* xg1 = (float*)(ob);                                     // [  0, 64M) [b*1024+t][2048]
  unsigned int* h1T = (unsigned int*)(ob + (64u << 20));         // [ 64, 80M) tagged u32
  unsigned int* h2T = (unsigned int*)(ob + (80u << 20));         // [ 80, 96M) tagged u32
  unsigned short* x_bf = (unsigned short*)(ob + (96u << 20));    // [ 96,104M)
  unsigned short* whh_bf = (unsigned short*)(ob + (104u << 20)); // [104,108M)
  unsigned short* wih_bf = (unsigned short*)(ob + (108u << 20)); // [108,112M)

  char* ws = (char*)d_ws;  // within proven 43 MiB footprint
  unsigned short* fcw_bf = (unsigned short*)(ws);                // [ 0,32M)
  float* bias12 = (float*)(ws + (32u << 20));                    // 16 KiB
  unsigned short* h2bf = (unsigned short*)(ws + (35u << 20));    // [35,43M) [t*8+b][512]

  hipMemsetAsync(ob + (64u << 20), 0, 32u << 20, stream);  // clear h tags (honest sync/replay)
  embed_kernel<<<8192, 256, 0, stream>>>(inp, wte, x_bf);
  cvt_bf16_kernel<<<2048, 256, 0, stream>>>(W_ih, wih_bf, 2 * 2048 * 512 / 4);
  cvt_bf16_kernel<<<2048, 256, 0, stream>>>(W_hh, whh_bf, 2 * 2048 * 512 / 4);
  cvt_bf16_kernel<<<16000, 256, 0, stream>>>(fc_w, fcw_bf, 32000 * 512 / 4);
  bias_sum_kernel<<<16, 256, 0, stream>>>(b_ih, b_hh, bias12, 4096);
  // xg1[b*1024+t][g] = x @ W_ih0^T + (b_ih0 + b_hh0)
  gemm_bt<0><<<64 * 16, 256, 0, stream>>>(x_bf, wih_bf, xg1, bias12, 8192, 2048, 512);
  lstm_fused<<<32, 256, 0, stream>>>(xg1, whh_bf, wih_bf + (size_t)2048 * 512,
                                     whh_bf + (size_t)2048 * 512, bias12 + 2048,
                                     h1T, h2T, h2bf);
  // logits = h2 @ fc_w^T + fc_b  (A rows t*8+b -> C rows b*1024+t)
  gemm_bt<1><<<64 * 250, 256, 0, stream>>>(h2bf, fcw_bf, out, fc_b, 8192, 32000, 512);
}